// Round 1
// baseline (489.257 us; speedup 1.0000x reference)
//
#include <hip/hip_runtime.h>
#include <math.h>

#define ALPHA 0.42f
#define H 1024
#define W 1024
#define NB 16
#define NS 3
#define NCH (NB * NS)
#define TILE 64
#define HALO 3
#define LDSW (TILE + 2 * HALO)   // 70
#define SM_STRIDE 72

// ---------------------------------------------------------------------------
// Kernel 1: per-channel score = ALPHA * sum(edge) + (1-ALPHA) * sum(local_var)
// edge from 3x3 sobel/laplacian on sigmoid(logits) (zero-padded SAME).
// local_var.sum collapses to sum_q (m0-mean)^2 * cnt(q)/49 where cnt = fx*fy.
// ---------------------------------------------------------------------------
__global__ __launch_bounds__(256, 4)
void score_kernel(const float* __restrict__ logits, float* __restrict__ scores) {
    __shared__ float sm[LDSW][SM_STRIDE];   // sigmoid tile + halo (70x70 used)
    __shared__ float rs[LDSW][TILE];        // 7-wide horizontal sums
    __shared__ float red[4];

    const int ch  = blockIdx.z;                  // b*3 + s
    const int ty0 = blockIdx.y * TILE;
    const int tx0 = blockIdx.x * TILE;
    const int tid = threadIdx.x;
    const float* img = logits + (size_t)ch * H * W;

    // Phase 1: load sigmoid with halo; literal 0.0 outside (JAX zero padding)
    for (int i = tid; i < LDSW * LDSW; i += 256) {
        int ly = i / LDSW, lx = i - ly * LDSW;
        int gy = ty0 + ly - HALO, gx = tx0 + lx - HALO;
        float v = 0.0f;
        if (gy >= 0 && gy < H && gx >= 0 && gx < W) {
            float x = img[(size_t)gy * W + gx];
            v = 1.0f / (1.0f + __expf(-x));
        }
        sm[ly][lx] = v;
    }
    __syncthreads();

    // Phase 2: horizontal 7-sums for every halo row, interior columns only
    for (int i = tid; i < LDSW * TILE; i += 256) {
        int ly = i / TILE, lx = i - ly * TILE;
        float s = 0.f;
        #pragma unroll
        for (int k = 0; k < 7; ++k) s += sm[ly][lx + k];
        rs[ly][lx] = s;
    }
    __syncthreads();

    // Phase 3: per-pixel contribution
    float acc = 0.f;
    for (int i = tid; i < TILE * TILE; i += 256) {
        int ty = i >> 6, tx = i & 63;
        int gy = ty0 + ty, gx = tx0 + tx;

        // 3x3 neighborhood a[dy][dx] = m[gy-1+dy][gx-1+dx]
        float a00 = sm[ty + 2][tx + 2], a01 = sm[ty + 2][tx + 3], a02 = sm[ty + 2][tx + 4];
        float a10 = sm[ty + 3][tx + 2], a11 = sm[ty + 3][tx + 3], a12 = sm[ty + 3][tx + 4];
        float a20 = sm[ty + 4][tx + 2], a21 = sm[ty + 4][tx + 3], a22 = sm[ty + 4][tx + 4];

        // cross-correlation with sobel_x / sobel_y / laplacian
        float sgx = a00 - a02 + 2.f * a10 - 2.f * a12 + a20 - a22;
        float sgy = a00 + 2.f * a01 + a02 - a20 - 2.f * a21 - a22;
        float lp  = a01 + a10 - 4.f * a11 + a12 + a21;
        float edge = sqrtf(sgx * sgx + sgy * sgy) + 0.5f * fabsf(lp);

        // 7x7 mean (always /49, zero-padded)
        float vs = rs[ty][tx] + rs[ty + 1][tx] + rs[ty + 2][tx] + rs[ty + 3][tx]
                 + rs[ty + 4][tx] + rs[ty + 5][tx] + rs[ty + 6][tx];
        float mean = vs * (1.f / 49.f);
        float d = a11 - mean;

        // number of 7x7 windows containing this pixel (separable)
        int fy = 7 - max(0, 3 - gy) - max(0, gy - (H - 4));
        int fx = 7 - max(0, 3 - gx) - max(0, gx - (W - 4));

        acc += ALPHA * edge + (1.f - ALPHA) * d * d * (float)(fx * fy) * (1.f / 49.f);
    }

    // wave reduce (64 lanes), then block reduce across 4 waves
    #pragma unroll
    for (int off = 32; off > 0; off >>= 1) acc += __shfl_down(acc, off);
    if ((tid & 63) == 0) red[tid >> 6] = acc;
    __syncthreads();
    if (tid == 0) {
        float t = red[0] + red[1] + red[2] + red[3];
        atomicAdd(&scores[ch], t);
    }
}

// ---------------------------------------------------------------------------
// Kernel 2: scores[48] + learnable[3] -> weights[48]
// ---------------------------------------------------------------------------
__global__ void weights_kernel(const float* __restrict__ scores,
                               const float* __restrict__ lw,
                               float* __restrict__ weights) {
    int t = threadIdx.x;
    float l0 = lw[0], l1 = lw[1], l2 = lw[2];
    float mx = fmaxf(l0, fmaxf(l1, l2));
    float e0 = __expf(l0 - mx), e1 = __expf(l1 - mx), e2 = __expf(l2 - mx);
    float inv = 1.f / (e0 + e1 + e2);
    float wl0 = e0 * inv, wl1 = e1 * inv, wl2 = e2 * inv;
    if (t < NB) {
        float s0 = scores[t * 3 + 0], s1 = scores[t * 3 + 1], s2 = scores[t * 3 + 2];
        float itot = 1.f / (s0 + s1 + s2 + 1e-6f);
        weights[t * 3 + 0] = 0.5f * (s0 * itot + wl0);
        weights[t * 3 + 1] = 0.5f * (s1 * itot + wl1);
        weights[t * 3 + 2] = 0.5f * (s2 * itot + wl2);
    }
}

// ---------------------------------------------------------------------------
// Kernel 3: out[b,h,w] = sum_s logits[b,s,h,w] * weights[b,s]  (float4)
// ---------------------------------------------------------------------------
__global__ __launch_bounds__(256)
void fuse_kernel(const float* __restrict__ logits,
                 const float* __restrict__ weights,
                 float* __restrict__ out) {
    const size_t HW = (size_t)H * W;
    size_t idx = ((size_t)blockIdx.x * blockDim.x + threadIdx.x) * 4;
    if (idx >= (size_t)NB * HW) return;
    size_t b = idx / HW;
    size_t r = idx - b * HW;
    float w0 = weights[b * 3 + 0];
    float w1 = weights[b * 3 + 1];
    float w2 = weights[b * 3 + 2];
    const float* base = logits + b * 3 * HW + r;
    float4 x0 = *(const float4*)(base);
    float4 x1 = *(const float4*)(base + HW);
    float4 x2 = *(const float4*)(base + 2 * HW);
    float4 o;
    o.x = x0.x * w0 + x1.x * w1 + x2.x * w2;
    o.y = x0.y * w0 + x1.y * w1 + x2.y * w2;
    o.z = x0.z * w0 + x1.z * w1 + x2.z * w2;
    o.w = x0.w * w0 + x1.w * w1 + x2.w * w2;
    *(float4*)(out + idx) = o;
}

extern "C" void kernel_launch(void* const* d_in, const int* in_sizes, int n_in,
                              void* d_out, int out_size, void* d_ws, size_t ws_size,
                              hipStream_t stream) {
    const float* logits = (const float*)d_in[0];
    const float* lw     = (const float*)d_in[1];
    float* out     = (float*)d_out;
    float* scores  = (float*)d_ws;          // 48 floats
    float* weights = scores + NCH;          // 48 floats

    hipMemsetAsync(d_ws, 0, NCH * sizeof(float), stream);

    dim3 g1(W / TILE, H / TILE, NCH);
    score_kernel<<<g1, 256, 0, stream>>>(logits, scores);

    weights_kernel<<<1, 64, 0, stream>>>(scores, lw, weights);

    size_t n4 = (size_t)NB * H * W / 4;
    fuse_kernel<<<(n4 + 255) / 256, 256, 0, stream>>>(logits, weights, out);
}

// Round 2
// 428.003 us; speedup vs baseline: 1.1431x; 1.1431x over previous
//
#include <hip/hip_runtime.h>
#include <math.h>

#define ALPHA 0.42f
#define H 1024
#define W 1024
#define NB 16
#define NCH 48
#define TILE 64
#define SMS 76          // sm row stride (floats); 76 % 32 = 12 banks skew
#define RSS 64          // rs row stride (floats)

__device__ __forceinline__ float sigmoidf(float x) {
    return 1.0f / (1.0f + __expf(-x));
}

// ---------------------------------------------------------------------------
// Kernel 1: per-channel score = ALPHA*sum(edge) + (1-ALPHA)*sum(local_var)
// Fully b128-vectorized LDS; phase-3 does 4x4 pixels/thread with register
// rolling of the 3x3 rows and the 7-row variance window.
// sm[r][idx]: sigmoid tile; idx = tile_col + 4 (cols -4..71; valid -3..66)
// rs[r][c]  : horizontal 7-sums; r = tile_row + 3 (rows -3..66), c = 0..63
// ---------------------------------------------------------------------------
__global__ __launch_bounds__(256, 4)
void score_kernel(const float* __restrict__ logits, float* __restrict__ scores) {
    __shared__ float sm[70 * SMS];   // 21280 B
    __shared__ float rs[70 * RSS];   // 17920 B
    __shared__ float red[4];

    const int ch  = blockIdx.z;
    const int ty0 = blockIdx.y * TILE;
    const int tx0 = blockIdx.x * TILE;
    const int tid = threadIdx.x;
    const float* img = logits + (size_t)ch * (H * W);

    // Phase 1a: interior columns, aligned float4 loads + vector sigmoid
    for (int i = tid; i < 70 * 16; i += 256) {
        int row = i >> 4;
        int c4  = (i & 15) << 2;
        int gy  = ty0 + row - 3;
        float4 s = make_float4(0.f, 0.f, 0.f, 0.f);
        if (gy >= 0 && gy < H) {
            float4 v = *(const float4*)(img + (size_t)gy * W + tx0 + c4);
            s.x = sigmoidf(v.x); s.y = sigmoidf(v.y);
            s.z = sigmoidf(v.z); s.w = sigmoidf(v.w);
        }
        *(float4*)&sm[row * SMS + c4 + 4] = s;
    }
    // Phase 1b: halo columns idx 0..3 (cols -4..-1) and 68..71 (cols 64..67)
    for (int i = tid; i < 70 * 8; i += 256) {
        int row = i >> 3;
        int k   = i & 7;
        int idx = (k < 4) ? k : (64 + k);
        int gx  = tx0 + idx - 4;
        int gy  = ty0 + row - 3;
        float s = 0.f;
        if (gx >= 0 && gx < W && gy >= 0 && gy < H)
            s = sigmoidf(img[(size_t)gy * W + gx]);
        sm[row * SMS + idx] = s;
    }
    __syncthreads();

    // Phase 2: horizontal 7-sums, 4 columns per thread via incremental prefix
    for (int i = tid; i < 70 * 16; i += 256) {
        int row = i >> 4;
        int c4  = (i & 15) << 2;
        const float* p = &sm[row * SMS + c4];
        float4 A  = *(const float4*)(p);        // idx c4..c4+3
        float4 Bv = *(const float4*)(p + 4);    // idx c4+4..c4+7
        float4 Cv = *(const float4*)(p + 8);    // idx c4+8..c4+11
        float r0 = A.y + A.z + A.w + Bv.x + Bv.y + Bv.z + Bv.w; // cols c4-3..c4+3
        float r1 = r0 - A.y + Cv.x;
        float r2 = r1 - A.z + Cv.y;
        float r3 = r2 - A.w + Cv.z;
        *(float4*)&rs[row * RSS + c4] = make_float4(r0, r1, r2, r3);
    }
    __syncthreads();

    // Phase 3: each thread owns a 4(cols) x 4(rows) patch
    const int cg = tid & 15;
    const int rg = tid >> 4;
    const int c4 = cg << 2;
    const int ys = rg << 2;   // first local row of patch (0..60)

    float fxf[4];
    #pragma unroll
    for (int j = 0; j < 4; ++j) {
        int gx = tx0 + c4 + j;
        int fx = 7 - max(0, 3 - gx) - max(0, gx - (W - 4));
        fxf[j] = (float)fx;
    }

    // init 7-row variance window sum (rs rows ys..ys+6), stash rows to subtract
    float4 vsv = make_float4(0.f, 0.f, 0.f, 0.f);
    float4 sub[3];
    #pragma unroll
    for (int k = 0; k < 7; ++k) {
        float4 r = *(const float4*)&rs[(ys + k) * RSS + c4];
        if (k < 3) sub[k] = r;
        vsv.x += r.x; vsv.y += r.y; vsv.z += r.z; vsv.w += r.w;
    }

    // rolling 3x3 rows: 6 useful floats per row (cols c4-1 .. c4+4)
    float ra[6], rb[6], rc[6];
    {
        const float* p = &sm[(ys + 2) * SMS + c4];
        float4 A = *(const float4*)(p); float4 Bv = *(const float4*)(p + 4); float4 Cc = *(const float4*)(p + 8);
        ra[0] = A.w; ra[1] = Bv.x; ra[2] = Bv.y; ra[3] = Bv.z; ra[4] = Bv.w; ra[5] = Cc.x;
    }
    {
        const float* p = &sm[(ys + 3) * SMS + c4];
        float4 A = *(const float4*)(p); float4 Bv = *(const float4*)(p + 4); float4 Cc = *(const float4*)(p + 8);
        rb[0] = A.w; rb[1] = Bv.x; rb[2] = Bv.y; rb[3] = Bv.z; rb[4] = Bv.w; rb[5] = Cc.x;
    }

    float acc = 0.f;
    #pragma unroll
    for (int y = 0; y < 4; ++y) {
        {
            const float* p = &sm[(ys + y + 4) * SMS + c4];
            float4 A = *(const float4*)(p); float4 Bv = *(const float4*)(p + 4); float4 Cc = *(const float4*)(p + 8);
            rc[0] = A.w; rc[1] = Bv.x; rc[2] = Bv.y; rc[3] = Bv.z; rc[4] = Bv.w; rc[5] = Cc.x;
        }
        int gy = ty0 + ys + y;
        int fy = 7 - max(0, 3 - gy) - max(0, gy - (H - 4));
        float wv = (1.0f - ALPHA) * (1.0f / 49.0f) * (float)fy;
        const float* vsp = &vsv.x;
        #pragma unroll
        for (int j = 0; j < 4; ++j) {
            float a00 = ra[j], a01 = ra[j + 1], a02 = ra[j + 2];
            float a10 = rb[j], a11 = rb[j + 1], a12 = rb[j + 2];
            float a20 = rc[j], a21 = rc[j + 1], a22 = rc[j + 2];
            float sgx = (a00 - a02) + 2.f * (a10 - a12) + (a20 - a22);
            float sgy = (a00 + 2.f * a01 + a02) - (a20 + 2.f * a21 + a22);
            float lp  = a01 + a10 + a12 + a21 - 4.f * a11;
            float edge = sqrtf(sgx * sgx + sgy * sgy) + 0.5f * fabsf(lp);
            float mean = vsp[j] * (1.f / 49.f);
            float d = a11 - mean;
            acc += ALPHA * edge + wv * fxf[j] * d * d;
        }
        #pragma unroll
        for (int t = 0; t < 6; ++t) { ra[t] = rb[t]; rb[t] = rc[t]; }
        if (y < 3) {
            float4 rn = *(const float4*)&rs[(ys + y + 7) * RSS + c4];
            vsv.x += rn.x - sub[y].x; vsv.y += rn.y - sub[y].y;
            vsv.z += rn.z - sub[y].z; vsv.w += rn.w - sub[y].w;
        }
    }

    // wave reduce (64 lanes) then block reduce (4 waves)
    #pragma unroll
    for (int off = 32; off > 0; off >>= 1) acc += __shfl_down(acc, off);
    if ((tid & 63) == 0) red[tid >> 6] = acc;
    __syncthreads();
    if (tid == 0) {
        atomicAdd(&scores[ch], red[0] + red[1] + red[2] + red[3]);
    }
}

// ---------------------------------------------------------------------------
// Kernel 2: fused weight computation + weighted channel sum (float4)
// ---------------------------------------------------------------------------
__global__ __launch_bounds__(256)
void fuse_kernel(const float* __restrict__ logits,
                 const float* __restrict__ scores,
                 const float* __restrict__ lw,
                 float* __restrict__ out) {
    const size_t HW = (size_t)H * W;
    size_t idx = ((size_t)blockIdx.x * blockDim.x + threadIdx.x) * 4;
    if (idx >= (size_t)NB * HW) return;
    size_t b = idx >> 20;            // HW = 2^20
    size_t r = idx & (HW - 1);

    // learnable softmax (uniform across threads; scalar-unit friendly)
    float l0 = lw[0], l1 = lw[1], l2 = lw[2];
    float mx = fmaxf(l0, fmaxf(l1, l2));
    float e0 = __expf(l0 - mx), e1 = __expf(l1 - mx), e2 = __expf(l2 - mx);
    float inv = 1.f / (e0 + e1 + e2);

    float s0 = scores[b * 3 + 0], s1 = scores[b * 3 + 1], s2 = scores[b * 3 + 2];
    float itot = 1.f / (s0 + s1 + s2 + 1e-6f);
    float w0 = 0.5f * (s0 * itot + e0 * inv);
    float w1 = 0.5f * (s1 * itot + e1 * inv);
    float w2 = 0.5f * (s2 * itot + e2 * inv);

    const float* base = logits + b * 3 * HW + r;
    float4 x0 = *(const float4*)(base);
    float4 x1 = *(const float4*)(base + HW);
    float4 x2 = *(const float4*)(base + 2 * HW);
    float4 o;
    o.x = x0.x * w0 + x1.x * w1 + x2.x * w2;
    o.y = x0.y * w0 + x1.y * w1 + x2.y * w2;
    o.z = x0.z * w0 + x1.z * w1 + x2.z * w2;
    o.w = x0.w * w0 + x1.w * w1 + x2.w * w2;
    *(float4*)(out + idx) = o;
}

extern "C" void kernel_launch(void* const* d_in, const int* in_sizes, int n_in,
                              void* d_out, int out_size, void* d_ws, size_t ws_size,
                              hipStream_t stream) {
    const float* logits = (const float*)d_in[0];
    const float* lw     = (const float*)d_in[1];
    float* out    = (float*)d_out;
    float* scores = (float*)d_ws;    // 48 floats

    hipMemsetAsync(d_ws, 0, NCH * sizeof(float), stream);

    dim3 g1(W / TILE, H / TILE, NCH);
    score_kernel<<<g1, 256, 0, stream>>>(logits, scores);

    size_t n4 = (size_t)NB * H * W / 4;
    fuse_kernel<<<(n4 + 255) / 256, 256, 0, stream>>>(logits, scores, lw, out);
}